// Round 5
// baseline (198.822 us; speedup 1.0000x reference)
//
#include <hip/hip_runtime.h>
#include <hip/hip_cooperative_groups.h>

namespace cg = cooperative_groups;

// Problem constants (match reference)
#define N_NODES 100000
#define E_EDGES 1600000
#define E4      (E_EDGES / 4)     // 400000 int4 elements
#define HD 64
#define CAP 128                   // capacity for in-edges of node 2 (~Poisson(16))
#define NBLOCKS 512
#define NTHREADS (NBLOCKS * 256)  // 131072

// Single fused cooperative kernel:
//  pre : block 0 zeroes ws counters; block 0 prefetches all weight columns to regs
//  A   : all threads hold their dst int4s in regs; collect srcs of edges into node 2
//  sort: every block sorts srclist into LDS (canonical order -> bitwise determinism)
//  B   : count degrees of the <=K+1 ids from the register-held dst values (LDS agg)
//  C   : block 0 computes the node-2 forward pass and writes the scalar
__global__ __launch_bounds__(256) void fused_kernel(
    const float* __restrict__ x,
    const float* __restrict__ Wz, const float* __restrict__ bz,
    const float* __restrict__ Wh, const float* __restrict__ bh,
    const float* __restrict__ LzW, const float* __restrict__ Lzb,
    const float* __restrict__ LhW, const float* __restrict__ Lhb,
    const float* __restrict__ W1, const float* __restrict__ b1,
    const float* __restrict__ gamma_, const float* __restrict__ beta_,
    const float* __restrict__ rmean, const float* __restrict__ rvar,
    const float* __restrict__ W2, const float* __restrict__ b2,
    const int* __restrict__ src, const int* __restrict__ dst,
    int* __restrict__ count, int* __restrict__ srclist, int* __restrict__ degs,
    float* __restrict__ out) {
    cg::grid_group grid = cg::this_grid();
    const int tid  = blockIdx.x * 256 + threadIdx.x;
    const int lane = threadIdx.x & 63;
    const int w    = threadIdx.x >> 6;     // wave id 0..3

    __shared__ int   ids[CAP + 1];
    __shared__ int   cnt[CAP + 1];
    __shared__ float s_part[4][HD];
    __shared__ float s_xsum[HD];
    __shared__ float s_cz[HD], s_ch[HD];
    __shared__ float s_r[HD];

    // ---- pre: zero ws (block 0) + weight prefetch to regs (block 0 only) ----
    if (blockIdx.x == 0) {
        for (int i = threadIdx.x; i < CAP + 1; i += 256) degs[i] = 0;
        if (threadIdx.x == 0) *count = 0;
    }
    float wB[32], wC[32], wD[16];
    if (blockIdx.x == 0) {
        const float* WB = (w < 2) ? Wz : Wh;
        const float* WC = (w < 2) ? LzW : LhW;
        const int k0 = (w & 1) * 32;
        #pragma unroll
        for (int kk = 0; kk < 32; ++kk) wB[kk] = WB[(size_t)(k0 + kk) * HD + lane];
        #pragma unroll
        for (int kk = 0; kk < 32; ++kk) wC[kk] = WC[(size_t)(k0 + kk) * HD + lane];
        #pragma unroll
        for (int kk = 0; kk < 16; ++kk) wD[kk] = W1[(size_t)(w * 16 + kk) * HD + lane];
    }

    // load my dst elements into registers (independent of ws zeroing)
    const int4* dst4 = (const int4*)dst;
    int4 d[4];
    int nel = 0;
    #pragma unroll
    for (int r = 0; r < 4; ++r) {
        const int e = tid + r * NTHREADS;
        if (e < E4) { d[r] = dst4[e]; nel = r + 1; }
    }

    grid.sync();

    // ---- Phase A: collect sources of edges into node 2 (order arbitrary) ----
    for (int r = 0; r < nel; ++r) {
        const int base = (tid + r * NTHREADS) * 4;
        if (d[r].x == 2) { int i = atomicAdd(count, 1); if (i < CAP) srclist[i] = src[base + 0]; }
        if (d[r].y == 2) { int i = atomicAdd(count, 1); if (i < CAP) srclist[i] = src[base + 1]; }
        if (d[r].z == 2) { int i = atomicAdd(count, 1); if (i < CAP) srclist[i] = src[base + 2]; }
        if (d[r].w == 2) { int i = atomicAdd(count, 1); if (i < CAP) srclist[i] = src[base + 3]; }
    }

    grid.sync();

    // ---- sort: canonical (ascending) order of srclist, per block in LDS ----
    int K = *count; if (K > CAP) K = CAP;
    const int tot = K + 1;
    for (int i = threadIdx.x; i < K; i += 256) ids[i] = srclist[i];
    __syncthreads();
    if (threadIdx.x == 0) {
        for (int i = 1; i < K; ++i) {            // insertion sort, K ~ 16
            const int v = ids[i];
            int p = i - 1;
            while (p >= 0 && ids[p] > v) { ids[p + 1] = ids[p]; --p; }
            ids[p + 1] = v;
        }
        ids[K] = 2;                              // node 2 at entry K
    }
    __syncthreads();
    for (int i = threadIdx.x; i < tot; i += 256) cnt[i] = 0;
    __syncthreads();

    // ---- Phase B: degrees of the sorted ids (int atomics: order-safe) ----
    for (int i = 0; i < tot; ++i) {
        const int id = ids[i];
        int m = 0;
        for (int r = 0; r < nel; ++r)
            m += (d[r].x == id) + (d[r].y == id) + (d[r].z == id) + (d[r].w == id);
        if (m) atomicAdd(&cnt[i], m);
    }
    __syncthreads();
    for (int i = threadIdx.x; i < tot; i += 256)
        if (cnt[i]) atomicAdd(&degs[i], cnt[i]);

    grid.sync();

    // ---- Phase C: node-2 forward (block 0 only; uses sorted LDS ids) ----
    if (blockIdx.x != 0) return;

    const int k0 = (w & 1) * 32;
    // degs counts in-edges only; reference deg = indeg + 1 (self-loop).
    const float dinv2 = rsqrtf((float)(degs[K] + 1));

    // weighted sum of x rows (edges strided across waves, sorted order)
    float px = 0.f;
    for (int i = w; i < K; i += 4) {
        const int s = ids[i];
        const float wt = rsqrtf((float)(degs[i] + 1)) * dinv2;
        px += wt * x[(size_t)s * HD + lane];
    }
    if (w == 0) px += (dinv2 * dinv2) * x[2 * HD + lane];   // self-loop
    s_part[w][lane] = px;
    __syncthreads();
    if (w == 0)
        s_xsum[lane] = s_part[0][lane] + s_part[1][lane] + s_part[2][lane] + s_part[3][lane];
    __syncthreads();

    // cz = xsum@Wz + bz ; ch = xsum@Wh + bh
    {
        float acc = 0.f;
        #pragma unroll
        for (int kk = 0; kk < 32; ++kk) acc += s_xsum[k0 + kk] * wB[kk];
        s_part[w][lane] = acc;
    }
    __syncthreads();
    if (w == 0)      s_cz[lane] = s_part[0][lane] + s_part[1][lane] + bz[lane];
    else if (w == 1) s_ch[lane] = s_part[2][lane] + s_part[3][lane] + bh[lane];
    __syncthreads();

    // gate linears (H0 = 0 -> only first HD rows of L matter)
    {
        const float* c = (w < 2) ? s_cz : s_ch;
        float acc = 0.f;
        #pragma unroll
        for (int kk = 0; kk < 32; ++kk) acc += c[k0 + kk] * wC[kk];
        s_part[w][lane] = acc;
    }
    __syncthreads();
    if (w == 0) {
        const float zdot = s_part[0][lane] + s_part[1][lane] + Lzb[lane];
        const float hdot = s_part[2][lane] + s_part[3][lane] + Lhb[lane];
        const float Zv = 1.f / (1.f + expf(-zdot));
        const float Ht = tanhf(hdot);
        s_r[lane] = fmaxf((1.f - Zv) * Ht, 0.f);   // h = (1-Z)*Ht (H0=0), relu
    }
    __syncthreads();

    // y1 = relu_out @ W1, k-quarter per wave
    {
        float acc = 0.f;
        #pragma unroll
        for (int kk = 0; kk < 16; ++kk) acc += s_r[w * 16 + kk] * wD[kk];
        s_part[w][lane] = acc;
    }
    __syncthreads();

    // BN(eval) + relu + dot with W2 (wave 0)
    if (w == 0) {
        float y1 = s_part[0][lane] + s_part[1][lane] + s_part[2][lane] + s_part[3][lane] + b1[lane];
        const float bn = (y1 - rmean[lane]) * rsqrtf(rvar[lane] + 1e-5f) * gamma_[lane] + beta_[lane];
        const float yr = fmaxf(bn, 0.f);
        float part = yr * W2[lane];
        #pragma unroll
        for (int off = 32; off > 0; off >>= 1)
            part += __shfl_down(part, off, 64);
        if (lane == 0) out[0] = part + b2[0];
    }
}

extern "C" void kernel_launch(void* const* d_in, const int* in_sizes, int n_in,
                              void* d_out, int out_size, void* d_ws, size_t ws_size,
                              hipStream_t stream) {
    const float* x     = (const float*)d_in[0];
    const float* Wz    = (const float*)d_in[1];
    const float* bz    = (const float*)d_in[2];
    // d_in[3]=Wr, d_in[4]=br: dead (R only scales H0==0)
    const float* Wh    = (const float*)d_in[5];
    const float* bh    = (const float*)d_in[6];
    const float* LzW   = (const float*)d_in[7];
    const float* Lzb   = (const float*)d_in[8];
    // d_in[9]=Lr_W, d_in[10]=Lr_b: dead
    const float* LhW   = (const float*)d_in[11];
    const float* Lhb   = (const float*)d_in[12];
    const float* W1    = (const float*)d_in[13];
    const float* b1    = (const float*)d_in[14];
    const float* gam   = (const float*)d_in[15];
    const float* bet   = (const float*)d_in[16];
    const float* rmean = (const float*)d_in[17];
    const float* rvar  = (const float*)d_in[18];
    const float* W2    = (const float*)d_in[19];
    const float* b2    = (const float*)d_in[20];
    const int*   src   = (const int*)d_in[21];
    const int*   dst   = (const int*)d_in[22];

    // ws layout: [count:16 ints][srclist:CAP ints][degs:CAP+1 ints]
    int* count   = (int*)d_ws;
    int* srclist = count + 16;
    int* degs    = srclist + CAP;
    float* outp  = (float*)d_out;

    void* kargs[] = {
        (void*)&x, (void*)&Wz, (void*)&bz, (void*)&Wh, (void*)&bh,
        (void*)&LzW, (void*)&Lzb, (void*)&LhW, (void*)&Lhb,
        (void*)&W1, (void*)&b1, (void*)&gam, (void*)&bet,
        (void*)&rmean, (void*)&rvar, (void*)&W2, (void*)&b2,
        (void*)&src, (void*)&dst,
        (void*)&count, (void*)&srclist, (void*)&degs, (void*)&outp
    };
    hipLaunchCooperativeKernel((void*)fused_kernel, dim3(NBLOCKS), dim3(256),
                               kargs, 0, stream);
}

// Round 6
// 42.285 us; speedup vs baseline: 4.7020x; 4.7020x over previous
//
#include <hip/hip_runtime.h>

// Problem constants (match reference)
#define N_NODES 100000
#define E_EDGES 1600000
#define E4      (E_EDGES / 4)   // 400000 int4 elements
#define HD 64
#define CAP 128                 // srclist capacity (indegree ~Poisson(16))
#define SORTMAX 64              // wave rank-sort handles K <= 64 (P(K>64) ~ 1e-20)
#define CL_BLOCKS 400           // collect grid
#define CF_BLOCKS 256           // count+final grid

// Dispatch 2: collect source nodes of edges into node 2 (order arbitrary;
// canonicalized by sorting in the next kernel).
__global__ __launch_bounds__(256) void collect_kernel(
    const int* __restrict__ src, const int* __restrict__ dst,
    int* __restrict__ count, int* __restrict__ srclist) {
    const int nt = CL_BLOCKS * 256;
    const int t = blockIdx.x * 256 + threadIdx.x;
    const int4* dst4 = (const int4*)dst;
    #pragma unroll
    for (int r = 0; r < 4; ++r) {
        const int e = t + r * nt;
        if (e < E4) {
            const int4 d = dst4[e];
            const int base = e * 4;
            if (d.x == 2) { int i = atomicAdd(count, 1); if (i < CAP) srclist[i] = src[base + 0]; }
            if (d.y == 2) { int i = atomicAdd(count, 1); if (i < CAP) srclist[i] = src[base + 1]; }
            if (d.z == 2) { int i = atomicAdd(count, 1); if (i < CAP) srclist[i] = src[base + 2]; }
            if (d.w == 2) { int i = atomicAdd(count, 1); if (i < CAP) srclist[i] = src[base + 3]; }
        }
    }
}

// Dispatch 3: degree count of the <=K+1 ids (grid-stride over dst) + the
// last block (ticket idiom) runs the node-2 forward pass.
__global__ __launch_bounds__(256) void countfinal_kernel(
    const float* __restrict__ x,
    const float* __restrict__ Wz, const float* __restrict__ bz,
    const float* __restrict__ Wh, const float* __restrict__ bh,
    const float* __restrict__ LzW, const float* __restrict__ Lzb,
    const float* __restrict__ LhW, const float* __restrict__ Lhb,
    const float* __restrict__ W1, const float* __restrict__ b1,
    const float* __restrict__ gamma_, const float* __restrict__ beta_,
    const float* __restrict__ rmean, const float* __restrict__ rvar,
    const float* __restrict__ W2, const float* __restrict__ b2,
    const int* __restrict__ dst,
    const int* __restrict__ count, const int* __restrict__ srclist,
    int* __restrict__ degs, int* __restrict__ done,
    float* __restrict__ out) {
    const int tid  = threadIdx.x;
    const int lane = tid & 63;
    const int w    = tid >> 6;

    __shared__ int   s_ids[SORTMAX + 1];
    __shared__ int   s_cnt[SORTMAX + 1];
    __shared__ int   s_dg [SORTMAX + 1];
    __shared__ int   s_last;
    __shared__ float s_part[4][HD];
    __shared__ float s_xsum[HD];
    __shared__ float s_cz[HD], s_ch[HD];
    __shared__ float s_r[HD];

    // ---- canonical (ascending) srclist via wave rank-sort, wave 0 ----
    int K = *count; if (K > SORTMAX) K = SORTMAX;
    const int tot = K + 1;
    if (tid < 64) {
        const int v = (tid < K) ? srclist[tid] : 0x7fffffff;
        int rank = 0;
        for (int j = 0; j < 64; ++j) {
            const int vj = __shfl(v, j, 64);
            rank += (vj < v) || (vj == v && j < tid);   // tie-break: lane index
        }
        if (tid < K) s_ids[rank] = v;
        if (tid == 0) s_ids[K] = 2;                     // node 2 at entry K
    }
    for (int i = tid; i < tot; i += 256) s_cnt[i] = 0;
    __syncthreads();

    // ---- degree scan: grid-stride over dst, match vs LDS ids ----
    const int4* dst4 = (const int4*)dst;
    const int stride = CF_BLOCKS * 256;
    for (int e = blockIdx.x * 256 + tid; e < E4; e += stride) {
        const int4 d = dst4[e];
        for (int i = 0; i < tot; ++i) {
            const int id = s_ids[i];
            const int m = (d.x == id) + (d.y == id) + (d.z == id) + (d.w == id);
            if (m) atomicAdd(&s_cnt[i], m);
        }
    }
    __syncthreads();
    for (int i = tid; i < tot; i += 256)
        if (s_cnt[i]) atomicAdd(&degs[i], s_cnt[i]);

    // ---- last-block ticket ----
    __threadfence();
    if (tid == 0) s_last = (atomicAdd(done, 1) == CF_BLOCKS - 1);
    __syncthreads();
    if (!s_last) return;

    // ---- final: node-2 forward (executor-independent, deterministic) ----
    // Atomic reads guarantee we see every block's aggregated degree.
    if (tid < tot) s_dg[tid] = atomicAdd(&degs[tid], 0);
    __syncthreads();

    const float* WB = (w < 2) ? Wz : Wh;
    const float* WC = (w < 2) ? LzW : LhW;
    const int k0 = (w & 1) * 32;
    float wB[32], wC[32], wD[16];
    #pragma unroll
    for (int kk = 0; kk < 32; ++kk) wB[kk] = WB[(size_t)(k0 + kk) * HD + lane];
    #pragma unroll
    for (int kk = 0; kk < 32; ++kk) wC[kk] = WC[(size_t)(k0 + kk) * HD + lane];
    #pragma unroll
    for (int kk = 0; kk < 16; ++kk) wD[kk] = W1[(size_t)(w * 16 + kk) * HD + lane];

    // reference deg = indeg + 1 (self-loop)
    const float dinv2 = rsqrtf((float)(s_dg[K] + 1));

    // weighted sum of x rows (sorted order, fixed wave-strided partition)
    float px = 0.f;
    for (int i = w; i < K; i += 4) {
        const int s = s_ids[i];
        const float wt = rsqrtf((float)(s_dg[i] + 1)) * dinv2;
        px += wt * x[(size_t)s * HD + lane];
    }
    if (w == 0) px += (dinv2 * dinv2) * x[2 * HD + lane];   // self-loop
    s_part[w][lane] = px;
    __syncthreads();
    if (w == 0)
        s_xsum[lane] = s_part[0][lane] + s_part[1][lane] + s_part[2][lane] + s_part[3][lane];
    __syncthreads();

    // cz = xsum@Wz + bz ; ch = xsum@Wh + bh
    {
        float acc = 0.f;
        #pragma unroll
        for (int kk = 0; kk < 32; ++kk) acc += s_xsum[k0 + kk] * wB[kk];
        s_part[w][lane] = acc;
    }
    __syncthreads();
    if (w == 0)      s_cz[lane] = s_part[0][lane] + s_part[1][lane] + bz[lane];
    else if (w == 1) s_ch[lane] = s_part[2][lane] + s_part[3][lane] + bh[lane];
    __syncthreads();

    // gate linears (H0 = 0 -> only first HD rows matter)
    {
        const float* c = (w < 2) ? s_cz : s_ch;
        float acc = 0.f;
        #pragma unroll
        for (int kk = 0; kk < 32; ++kk) acc += c[k0 + kk] * wC[kk];
        s_part[w][lane] = acc;
    }
    __syncthreads();
    if (w == 0) {
        const float zdot = s_part[0][lane] + s_part[1][lane] + Lzb[lane];
        const float hdot = s_part[2][lane] + s_part[3][lane] + Lhb[lane];
        const float Zv = 1.f / (1.f + expf(-zdot));
        const float Ht = tanhf(hdot);
        s_r[lane] = fmaxf((1.f - Zv) * Ht, 0.f);   // h = (1-Z)*Ht (H0=0), relu
    }
    __syncthreads();

    // y1 = relu_out @ W1, k-quarter per wave
    {
        float acc = 0.f;
        #pragma unroll
        for (int kk = 0; kk < 16; ++kk) acc += s_r[w * 16 + kk] * wD[kk];
        s_part[w][lane] = acc;
    }
    __syncthreads();

    // BN(eval) + relu + dot with W2 (wave 0)
    if (w == 0) {
        float y1 = s_part[0][lane] + s_part[1][lane] + s_part[2][lane] + s_part[3][lane] + b1[lane];
        const float bn = (y1 - rmean[lane]) * rsqrtf(rvar[lane] + 1e-5f) * gamma_[lane] + beta_[lane];
        const float yr = fmaxf(bn, 0.f);
        float part = yr * W2[lane];
        #pragma unroll
        for (int off = 32; off > 0; off >>= 1)
            part += __shfl_down(part, off, 64);
        if (lane == 0) out[0] = part + b2[0];
    }
}

extern "C" void kernel_launch(void* const* d_in, const int* in_sizes, int n_in,
                              void* d_out, int out_size, void* d_ws, size_t ws_size,
                              hipStream_t stream) {
    const float* x     = (const float*)d_in[0];
    const float* Wz    = (const float*)d_in[1];
    const float* bz    = (const float*)d_in[2];
    // d_in[3]=Wr, d_in[4]=br: dead (R only scales H0==0)
    const float* Wh    = (const float*)d_in[5];
    const float* bh    = (const float*)d_in[6];
    const float* LzW   = (const float*)d_in[7];
    const float* Lzb   = (const float*)d_in[8];
    // d_in[9]=Lr_W, d_in[10]=Lr_b: dead
    const float* LhW   = (const float*)d_in[11];
    const float* Lhb   = (const float*)d_in[12];
    const float* W1    = (const float*)d_in[13];
    const float* b1    = (const float*)d_in[14];
    const float* gam   = (const float*)d_in[15];
    const float* bet   = (const float*)d_in[16];
    const float* rmean = (const float*)d_in[17];
    const float* rvar  = (const float*)d_in[18];
    const float* W2    = (const float*)d_in[19];
    const float* b2    = (const float*)d_in[20];
    const int*   src   = (const int*)d_in[21];
    const int*   dst   = (const int*)d_in[22];

    // ws layout (ints): [count:16][srclist:CAP][degs:SORTMAX+1 -> at 144][done: at 224]
    int* count   = (int*)d_ws;
    int* srclist = count + 16;
    int* degs    = count + 144;
    int* done    = count + 224;
    hipMemsetAsync(d_ws, 0, 240 * sizeof(int), stream);

    collect_kernel<<<CL_BLOCKS, 256, 0, stream>>>(src, dst, count, srclist);

    countfinal_kernel<<<CF_BLOCKS, 256, 0, stream>>>(
        x, Wz, bz, Wh, bh, LzW, Lzb, LhW, Lhb,
        W1, b1, gam, bet, rmean, rvar, W2, b2,
        dst, count, srclist, degs, done, (float*)d_out);
}

// Round 7
// 31.312 us; speedup vs baseline: 6.3498x; 1.3504x over previous
//
#include <hip/hip_runtime.h>
#include <limits.h>

// Problem constants (match reference)
#define N_NODES 100000
#define E_EDGES 1600000
#define E4      (E_EDGES / 4)   // 400000 int4 elements
#define HD 64
#define SORTMAX 64              // K <= 64 (indegree ~Poisson(16); P(K>64) ~ 1e-20)
#define B1 1563                 // collect grid: 1563*256 = 400128 >= E4
#define B2 256                  // degree-scan grid
#define PERBLK 8                // max dst==2 matches per collect block (1024 edges)

// ws layout (int offsets) — every word consumed is written every launch:
#define OFF_BLKCNT 0            // [B1]
#define OFF_BLKSRC 1600         // [B1*PERBLK] = 12504
#define OFF_GK     14336        // [1]
#define OFF_GIDS   14337        // [SORTMAX+1]
#define OFF_DEGP   14464        // [(SORTMAX+1)*B2] transposed: degpart[i*B2+g]

// Dispatch 1: per-block collect of sources of edges into node 2.
// Plain stores only; blkcnt written unconditionally -> no ws pre-zeroing.
__global__ __launch_bounds__(256) void collect_kernel(
    const int* __restrict__ src, const int* __restrict__ dst,
    int* __restrict__ ws) {
    __shared__ int s_bn;
    __shared__ int s_bs[PERBLK];
    const int tid = threadIdx.x;
    if (tid == 0) s_bn = 0;
    __syncthreads();
    const int e = blockIdx.x * 256 + tid;
    if (e < E4) {
        const int4 d = ((const int4*)dst)[e];
        const int base = e * 4;
        if (d.x == 2) { int i = atomicAdd(&s_bn, 1); if (i < PERBLK) s_bs[i] = src[base + 0]; }
        if (d.y == 2) { int i = atomicAdd(&s_bn, 1); if (i < PERBLK) s_bs[i] = src[base + 1]; }
        if (d.z == 2) { int i = atomicAdd(&s_bn, 1); if (i < PERBLK) s_bs[i] = src[base + 2]; }
        if (d.w == 2) { int i = atomicAdd(&s_bn, 1); if (i < PERBLK) s_bs[i] = src[base + 3]; }
    }
    __syncthreads();
    const int bn = (s_bn < PERBLK) ? s_bn : PERBLK;
    if (tid == 0) ws[OFF_BLKCNT + blockIdx.x] = bn;
    if (tid < bn) ws[OFF_BLKSRC + blockIdx.x * PERBLK + tid] = s_bs[tid];
}

// Dispatch 2: gather srclist from per-block lists, canonical sort, degree scan.
// Per-block partial degrees stored with plain writes (no pre-zeroed globals).
__global__ __launch_bounds__(256) void count_kernel(
    const int* __restrict__ dst, int* __restrict__ ws) {
    __shared__ int s_n;
    __shared__ int s_ids[SORTMAX + 1];
    __shared__ int s_cnt[SORTMAX + 1];
    const int tid = threadIdx.x;
    if (tid == 0) s_n = 0;
    __syncthreads();

    // gather (order arbitrary; canonicalized by sort below)
    for (int b = tid; b < B1; b += 256) {
        int c = ws[OFF_BLKCNT + b];
        for (int q = 0; q < c; ++q) {
            const int slot = atomicAdd(&s_n, 1);
            if (slot < SORTMAX) s_ids[slot] = ws[OFF_BLKSRC + b * PERBLK + q];
        }
    }
    __syncthreads();
    const int K = (s_n < SORTMAX) ? s_n : SORTMAX;
    const int tot = K + 1;

    // wave-0 rank sort -> identical canonical array in every block
    if (tid < 64) {
        const int v = (tid < K) ? s_ids[tid] : INT_MAX;
        int rank = 0;
        for (int j = 0; j < 64; ++j) {
            const int vj = __shfl(v, j, 64);
            rank += (vj < v) || (vj == v && j < tid);
        }
        if (tid < K) s_ids[rank] = v;       // values already in regs; safe
        if (tid == 0) s_ids[K] = 2;         // node 2 at entry K
    }
    __syncthreads();
    for (int i = tid; i < tot; i += 256) s_cnt[i] = 0;
    __syncthreads();

    // grid-stride degree scan over dst
    const int4* dst4 = (const int4*)dst;
    for (int e = blockIdx.x * 256 + tid; e < E4; e += B2 * 256) {
        const int4 d = dst4[e];
        for (int i = 0; i < tot; ++i) {
            const int id = s_ids[i];
            const int m = (d.x == id) + (d.y == id) + (d.z == id) + (d.w == id);
            if (m) atomicAdd(&s_cnt[i], m);
        }
    }
    __syncthreads();
    // plain-store partials (transposed for final's coalesced-ish read)
    for (int i = tid; i < tot; i += 256)
        ws[OFF_DEGP + i * B2 + blockIdx.x] = s_cnt[i];
    if (blockIdx.x == 0) {
        for (int i = tid; i < tot; i += 256) ws[OFF_GIDS + i] = s_ids[i];
        if (tid == 0) ws[OFF_GK] = K;
    }
}

// Dispatch 3: node-2 forward. One block, 256 threads; lane j owns channel j.
__global__ __launch_bounds__(256) void final_kernel(
    const float* __restrict__ x,
    const float* __restrict__ Wz, const float* __restrict__ bz,
    const float* __restrict__ Wh, const float* __restrict__ bh,
    const float* __restrict__ LzW, const float* __restrict__ Lzb,
    const float* __restrict__ LhW, const float* __restrict__ Lhb,
    const float* __restrict__ W1, const float* __restrict__ b1,
    const float* __restrict__ gamma_, const float* __restrict__ beta_,
    const float* __restrict__ rmean, const float* __restrict__ rvar,
    const float* __restrict__ W2, const float* __restrict__ b2,
    const int* __restrict__ ws,
    float* __restrict__ out) {
    const int tid  = threadIdx.x;
    const int lane = tid & 63;
    const int w    = tid >> 6;

    __shared__ int   s_ids[SORTMAX + 1];
    __shared__ int   s_dg [SORTMAX + 1];
    __shared__ float s_part[4][HD];
    __shared__ float s_xsum[HD];
    __shared__ float s_cz[HD], s_ch[HD];
    __shared__ float s_r[HD];

    // weight prefetch first: data-independent, hides under the ws-dependent chain
    const float* WB = (w < 2) ? Wz : Wh;
    const float* WC = (w < 2) ? LzW : LhW;
    const int k0 = (w & 1) * 32;
    float wB[32], wC[32], wD[16];
    #pragma unroll
    for (int kk = 0; kk < 32; ++kk) wB[kk] = WB[(size_t)(k0 + kk) * HD + lane];
    #pragma unroll
    for (int kk = 0; kk < 32; ++kk) wC[kk] = WC[(size_t)(k0 + kk) * HD + lane];
    #pragma unroll
    for (int kk = 0; kk < 16; ++kk) wD[kk] = W1[(size_t)(w * 16 + kk) * HD + lane];

    const int K = ws[OFF_GK];
    const int tot = K + 1;
    if (tid < tot) s_ids[tid] = ws[OFF_GIDS + tid];

    // sum integer degree partials: 8 threads per id, 32 ids covered
    {
        const int i = tid >> 3, sub = tid & 7;
        int acc = 0;
        if (i < tot)
            for (int g = sub; g < B2; g += 8) acc += ws[OFF_DEGP + i * B2 + g];
        #pragma unroll
        for (int off = 4; off > 0; off >>= 1) acc += __shfl_down(acc, off, 8);
        if (sub == 0 && i < tot) s_dg[i] = acc;
        // ids 32..64: second pass (K>31 is rare but possible)
        const int i2 = i + 32;
        int acc2 = 0;
        if (i2 < tot)
            for (int g = sub; g < B2; g += 8) acc2 += ws[OFF_DEGP + i2 * B2 + g];
        #pragma unroll
        for (int off = 4; off > 0; off >>= 1) acc2 += __shfl_down(acc2, off, 8);
        if (sub == 0 && i2 < tot) s_dg[i2] = acc2;
    }
    __syncthreads();

    // reference deg = indeg + 1 (self-loop)
    const float dinv2 = rsqrtf((float)(s_dg[K] + 1));

    // weighted x-row sum in canonical sorted order, fixed wave partition
    float px = 0.f;
    for (int i = w; i < K; i += 4) {
        const int s = s_ids[i];
        const float wt = rsqrtf((float)(s_dg[i] + 1)) * dinv2;
        px += wt * x[(size_t)s * HD + lane];
    }
    if (w == 0) px += (dinv2 * dinv2) * x[2 * HD + lane];   // self-loop
    s_part[w][lane] = px;
    __syncthreads();
    if (w == 0)
        s_xsum[lane] = s_part[0][lane] + s_part[1][lane] + s_part[2][lane] + s_part[3][lane];
    __syncthreads();

    // cz = xsum@Wz + bz ; ch = xsum@Wh + bh
    {
        float acc = 0.f;
        #pragma unroll
        for (int kk = 0; kk < 32; ++kk) acc += s_xsum[k0 + kk] * wB[kk];
        s_part[w][lane] = acc;
    }
    __syncthreads();
    if (w == 0)      s_cz[lane] = s_part[0][lane] + s_part[1][lane] + bz[lane];
    else if (w == 1) s_ch[lane] = s_part[2][lane] + s_part[3][lane] + bh[lane];
    __syncthreads();

    // gate linears (H0 = 0 -> only first HD rows matter)
    {
        const float* c = (w < 2) ? s_cz : s_ch;
        float acc = 0.f;
        #pragma unroll
        for (int kk = 0; kk < 32; ++kk) acc += c[k0 + kk] * wC[kk];
        s_part[w][lane] = acc;
    }
    __syncthreads();
    if (w == 0) {
        const float zdot = s_part[0][lane] + s_part[1][lane] + Lzb[lane];
        const float hdot = s_part[2][lane] + s_part[3][lane] + Lhb[lane];
        const float Zv = 1.f / (1.f + expf(-zdot));
        const float Ht = tanhf(hdot);
        s_r[lane] = fmaxf((1.f - Zv) * Ht, 0.f);   // h = (1-Z)*Ht (H0=0), relu
    }
    __syncthreads();

    // y1 = relu_out @ W1, k-quarter per wave
    {
        float acc = 0.f;
        #pragma unroll
        for (int kk = 0; kk < 16; ++kk) acc += s_r[w * 16 + kk] * wD[kk];
        s_part[w][lane] = acc;
    }
    __syncthreads();

    // BN(eval) + relu + dot with W2 (wave 0)
    if (w == 0) {
        float y1 = s_part[0][lane] + s_part[1][lane] + s_part[2][lane] + s_part[3][lane] + b1[lane];
        const float bn = (y1 - rmean[lane]) * rsqrtf(rvar[lane] + 1e-5f) * gamma_[lane] + beta_[lane];
        const float yr = fmaxf(bn, 0.f);
        float part = yr * W2[lane];
        #pragma unroll
        for (int off = 32; off > 0; off >>= 1)
            part += __shfl_down(part, off, 64);
        if (lane == 0) out[0] = part + b2[0];
    }
}

extern "C" void kernel_launch(void* const* d_in, const int* in_sizes, int n_in,
                              void* d_out, int out_size, void* d_ws, size_t ws_size,
                              hipStream_t stream) {
    const float* x     = (const float*)d_in[0];
    const float* Wz    = (const float*)d_in[1];
    const float* bz    = (const float*)d_in[2];
    // d_in[3]=Wr, d_in[4]=br: dead (R only scales H0==0)
    const float* Wh    = (const float*)d_in[5];
    const float* bh    = (const float*)d_in[6];
    const float* LzW   = (const float*)d_in[7];
    const float* Lzb   = (const float*)d_in[8];
    // d_in[9]=Lr_W, d_in[10]=Lr_b: dead
    const float* LhW   = (const float*)d_in[11];
    const float* Lhb   = (const float*)d_in[12];
    const float* W1    = (const float*)d_in[13];
    const float* b1    = (const float*)d_in[14];
    const float* gam   = (const float*)d_in[15];
    const float* bet   = (const float*)d_in[16];
    const float* rmean = (const float*)d_in[17];
    const float* rvar  = (const float*)d_in[18];
    const float* W2    = (const float*)d_in[19];
    const float* b2    = (const float*)d_in[20];
    const int*   src   = (const int*)d_in[21];
    const int*   dst   = (const int*)d_in[22];

    int* ws = (int*)d_ws;

    collect_kernel<<<B1, 256, 0, stream>>>(src, dst, ws);
    count_kernel<<<B2, 256, 0, stream>>>(dst, ws);
    final_kernel<<<1, 256, 0, stream>>>(x, Wz, bz, Wh, bh, LzW, Lzb, LhW, Lhb,
                                        W1, b1, gam, bet, rmean, rvar, W2, b2,
                                        ws, (float*)d_out);
}

// Round 8
// 25.540 us; speedup vs baseline: 7.7846x; 1.2260x over previous
//
#include <hip/hip_runtime.h>
#include <limits.h>

// Problem constants (match reference)
#define N_NODES 100000
#define E_EDGES 1600000
#define HD 64
#define CAP 128       // capacity for edges with dst==2 (indegree ~Poisson(16))
#define SORTMAX 64    // rank-sort capacity (P(K>64) ~ 1e-20)

// Pass 1: collect source nodes of edges into node 2. (R2-proven)
__global__ void collect_kernel(const int* __restrict__ src,
                               const int* __restrict__ dst,
                               int* __restrict__ count,
                               int* __restrict__ srclist) {
    int e4 = blockIdx.x * blockDim.x + threadIdx.x;
    const int4* dst4 = (const int4*)dst;
    if (e4 < E_EDGES / 4) {
        int4 d = dst4[e4];
        int base = e4 * 4;
        if (d.x == 2) { int i = atomicAdd(count, 1); if (i < CAP) srclist[i] = src[base + 0]; }
        if (d.y == 2) { int i = atomicAdd(count, 1); if (i < CAP) srclist[i] = src[base + 1]; }
        if (d.z == 2) { int i = atomicAdd(count, 1); if (i < CAP) srclist[i] = src[base + 2]; }
        if (d.w == 2) { int i = atomicAdd(count, 1); if (i < CAP) srclist[i] = src[base + 3]; }
    }
}

// Pass 2: in-degrees of the K srclist nodes + node 2 (entry K). (R2-proven)
// degs[i] pairs positionally with srclist[i]; integer atomics -> order-safe.
__global__ void count_kernel(const int* __restrict__ dst,
                             const int* __restrict__ count,
                             const int* __restrict__ srclist,
                             int* __restrict__ degs) {
    __shared__ int ids[CAP + 1];
    __shared__ int cnt[CAP + 1];
    int K = *count; if (K > CAP) K = CAP;
    const int tot = K + 1;
    for (int i = threadIdx.x; i < tot; i += blockDim.x) {
        ids[i] = (i < K) ? srclist[i] : 2;
        cnt[i] = 0;
    }
    __syncthreads();
    const int4* dst4 = (const int4*)dst;
    const int stride = gridDim.x * blockDim.x;
    for (int e4 = blockIdx.x * blockDim.x + threadIdx.x; e4 < E_EDGES / 4; e4 += stride) {
        int4 d = dst4[e4];
        for (int i = 0; i < tot; ++i) {
            const int id = ids[i];
            int m = (d.x == id) + (d.y == id) + (d.z == id) + (d.w == id);
            if (m) atomicAdd(&cnt[i], m);
        }
    }
    __syncthreads();
    for (int i = threadIdx.x; i < tot; i += blockDim.x)
        if (cnt[i]) atomicAdd(&degs[i], cnt[i]);
}

// Pass 3: node-2-only forward. 256 threads = 4 waves; lane j owns channel j.
// NEW vs R2: wave-0 rank-sorts the (srclist, degs) pairs into canonical
// ascending-id order before the fp sum -> bitwise determinism regardless of
// the atomic slot-grab order in collect_kernel (R4 tripwire fix).
__global__ __launch_bounds__(256) void final_kernel(
    const float* __restrict__ x,
    const float* __restrict__ Wz, const float* __restrict__ bz,
    const float* __restrict__ Wh, const float* __restrict__ bh,
    const float* __restrict__ LzW, const float* __restrict__ Lzb,
    const float* __restrict__ LhW, const float* __restrict__ Lhb,
    const float* __restrict__ W1, const float* __restrict__ b1,
    const float* __restrict__ gamma_, const float* __restrict__ beta_,
    const float* __restrict__ rmean, const float* __restrict__ rvar,
    const float* __restrict__ W2, const float* __restrict__ b2,
    const int* __restrict__ count, const int* __restrict__ srclist,
    const int* __restrict__ degs,
    float* __restrict__ out) {
    const int tid  = threadIdx.x;
    const int lane = tid & 63;
    const int w    = tid >> 6;          // wave id 0..3

    __shared__ int   s_ids[SORTMAX + 1];
    __shared__ int   s_dg [SORTMAX + 1];
    __shared__ float s_part[4][HD];
    __shared__ float s_xsum[HD];
    __shared__ float s_cz[HD], s_ch[HD];
    __shared__ float s_r[HD];

    // ---- Prefetch all weight columns into registers (data-independent) ----
    const float* WB = (w < 2) ? Wz : Wh;
    const float* WC = (w < 2) ? LzW : LhW;
    const int k0 = (w & 1) * 32;
    float wB[32], wC[32], wD[16];
    #pragma unroll
    for (int kk = 0; kk < 32; ++kk) wB[kk] = WB[(size_t)(k0 + kk) * HD + lane];
    #pragma unroll
    for (int kk = 0; kk < 32; ++kk) wC[kk] = WC[(size_t)(k0 + kk) * HD + lane];
    #pragma unroll
    for (int kk = 0; kk < 16; ++kk) wD[kk] = W1[(size_t)(w * 16 + kk) * HD + lane];

    int K = *count; if (K > SORTMAX) K = SORTMAX;

    // ---- canonical sort of (id, deg) pairs, wave 0 ----
    if (tid < 64) {
        const int v  = (tid < K) ? srclist[tid] : INT_MAX;
        const int dg = (tid < K) ? degs[tid]    : 0;
        int rank = 0;
        for (int j = 0; j < 64; ++j) {
            const int vj = __shfl(v, j, 64);
            rank += (vj < v) || (vj == v && j < tid);   // ties: equal id => equal deg
        }
        if (tid < K) { s_ids[rank] = v; s_dg[rank] = dg; }
        if (tid == 0) { s_ids[K] = 2; s_dg[K] = degs[K]; }
    }
    __syncthreads();

    // reference deg = indeg + 1 (self-loop)
    const float dinv2 = rsqrtf((float)(s_dg[K] + 1));

    // ---- weighted sum of x rows (sorted order, fixed wave partition) ----
    float px = 0.f;
    for (int i = w; i < K; i += 4) {
        const int s = s_ids[i];
        const float wt = rsqrtf((float)(s_dg[i] + 1)) * dinv2;
        px += wt * x[(size_t)s * HD + lane];
    }
    if (w == 0) px += (dinv2 * dinv2) * x[2 * HD + lane];   // self-loop
    s_part[w][lane] = px;
    __syncthreads();
    if (w == 0)
        s_xsum[lane] = s_part[0][lane] + s_part[1][lane] + s_part[2][lane] + s_part[3][lane];
    __syncthreads();

    // ---- cz = xsum@Wz + bz ; ch = xsum@Wh + bh ----
    {
        float acc = 0.f;
        #pragma unroll
        for (int kk = 0; kk < 32; ++kk) acc += s_xsum[k0 + kk] * wB[kk];
        s_part[w][lane] = acc;
    }
    __syncthreads();
    if (w == 0)      s_cz[lane] = s_part[0][lane] + s_part[1][lane] + bz[lane];
    else if (w == 1) s_ch[lane] = s_part[2][lane] + s_part[3][lane] + bh[lane];
    __syncthreads();

    // ---- gate linears (H0 = 0 -> only first HD rows matter) ----
    {
        const float* c = (w < 2) ? s_cz : s_ch;
        float acc = 0.f;
        #pragma unroll
        for (int kk = 0; kk < 32; ++kk) acc += c[k0 + kk] * wC[kk];
        s_part[w][lane] = acc;
    }
    __syncthreads();
    if (w == 0) {
        const float zdot = s_part[0][lane] + s_part[1][lane] + Lzb[lane];
        const float hdot = s_part[2][lane] + s_part[3][lane] + Lhb[lane];
        const float Zv = 1.f / (1.f + expf(-zdot));
        const float Ht = tanhf(hdot);
        s_r[lane] = fmaxf((1.f - Zv) * Ht, 0.f);   // h = (1-Z)*Ht (H0=0), relu
    }
    __syncthreads();

    // ---- y1 = relu_out @ W1, k-quarter per wave ----
    {
        float acc = 0.f;
        #pragma unroll
        for (int kk = 0; kk < 16; ++kk) acc += s_r[w * 16 + kk] * wD[kk];
        s_part[w][lane] = acc;
    }
    __syncthreads();

    // ---- BN(eval) + relu + dot with W2 (wave 0) ----
    if (w == 0) {
        float y1 = s_part[0][lane] + s_part[1][lane] + s_part[2][lane] + s_part[3][lane] + b1[lane];
        const float bn = (y1 - rmean[lane]) * rsqrtf(rvar[lane] + 1e-5f) * gamma_[lane] + beta_[lane];
        const float yr = fmaxf(bn, 0.f);
        float part = yr * W2[lane];
        #pragma unroll
        for (int off = 32; off > 0; off >>= 1)
            part += __shfl_down(part, off, 64);
        if (lane == 0) out[0] = part + b2[0];
    }
}

extern "C" void kernel_launch(void* const* d_in, const int* in_sizes, int n_in,
                              void* d_out, int out_size, void* d_ws, size_t ws_size,
                              hipStream_t stream) {
    const float* x     = (const float*)d_in[0];
    const float* Wz    = (const float*)d_in[1];
    const float* bz    = (const float*)d_in[2];
    // d_in[3]=Wr, d_in[4]=br: dead (R only scales H0==0)
    const float* Wh    = (const float*)d_in[5];
    const float* bh    = (const float*)d_in[6];
    const float* LzW   = (const float*)d_in[7];
    const float* Lzb   = (const float*)d_in[8];
    // d_in[9]=Lr_W, d_in[10]=Lr_b: dead
    const float* LhW   = (const float*)d_in[11];
    const float* Lhb   = (const float*)d_in[12];
    const float* W1    = (const float*)d_in[13];
    const float* b1    = (const float*)d_in[14];
    const float* gam   = (const float*)d_in[15];
    const float* bet   = (const float*)d_in[16];
    const float* rmean = (const float*)d_in[17];
    const float* rvar  = (const float*)d_in[18];
    const float* W2    = (const float*)d_in[19];
    const float* b2    = (const float*)d_in[20];
    const int*   src   = (const int*)d_in[21];
    const int*   dst   = (const int*)d_in[22];

    // ws layout: [count:16 ints][srclist:CAP ints][degs:CAP+1 ints]
    int* count   = (int*)d_ws;
    int* srclist = count + 16;
    int* degs    = srclist + CAP;
    const size_t zero_bytes = (size_t)(16 + CAP + CAP + 1) * sizeof(int);
    hipMemsetAsync(d_ws, 0, zero_bytes, stream);

    const int nthreads = 256;
    const int work = E_EDGES / 4;                         // 400K int4 elements
    const int nblocks = (work + nthreads - 1) / nthreads; // 1563
    collect_kernel<<<nblocks, nthreads, 0, stream>>>(src, dst, count, srclist);
    count_kernel<<<1024, nthreads, 0, stream>>>(dst, count, srclist, degs);

    final_kernel<<<1, 256, 0, stream>>>(x, Wz, bz, Wh, bh, LzW, Lzb, LhW, Lhb,
                                        W1, b1, gam, bet, rmean, rvar, W2, b2,
                                        count, srclist, degs, (float*)d_out);
}

// Round 9
// 24.461 us; speedup vs baseline: 8.1280x; 1.0441x over previous
//
#include <hip/hip_runtime.h>
#include <limits.h>

// Problem constants (match reference)
#define N_NODES 100000
#define E_EDGES 1600000
#define E4      (E_EDGES / 4)   // 400000 int4 elements
#define HD 64
#define SORTMAX 64              // K <= 64 (indegree ~Poisson(16); P(K>64) ~ 1e-20)
#define B1 1563                 // collect grid: 1563*256 >= E4
#define B2 1024                 // degree-scan grid (R2-proven)
#define PERBLK 8                // max dst==2 matches per collect block (1024 edges)

// ws layout (int offsets) — every consumed word written every launch:
#define OFF_BLKCNT 0            // [B1]
#define OFF_BLKSRC 1600         // [B1*PERBLK]
#define OFF_GK     14336        // [1]
#define OFF_GIDS   14400        // [SORTMAX+1]
#define OFF_DEGS   14528        // [SORTMAX+1] (zeroed by collect block 0)

// Dispatch 1: per-block collect of sources of edges into node 2.
// LDS slot-grab + plain stores -> no pre-zeroed globals needed.
// Block 0 also zeroes degs for the next dispatch's atomics.
__global__ __launch_bounds__(256) void collect_kernel(
    const int* __restrict__ src, const int* __restrict__ dst,
    int* __restrict__ ws) {
    __shared__ int s_bn;
    __shared__ int s_bs[PERBLK];
    const int tid = threadIdx.x;
    if (tid == 0) s_bn = 0;
    __syncthreads();
    const int e = blockIdx.x * 256 + tid;
    if (e < E4) {
        const int4 d = ((const int4*)dst)[e];
        const int base = e * 4;
        if (d.x == 2) { int i = atomicAdd(&s_bn, 1); if (i < PERBLK) s_bs[i] = src[base + 0]; }
        if (d.y == 2) { int i = atomicAdd(&s_bn, 1); if (i < PERBLK) s_bs[i] = src[base + 1]; }
        if (d.z == 2) { int i = atomicAdd(&s_bn, 1); if (i < PERBLK) s_bs[i] = src[base + 2]; }
        if (d.w == 2) { int i = atomicAdd(&s_bn, 1); if (i < PERBLK) s_bs[i] = src[base + 3]; }
    }
    __syncthreads();
    const int bn = (s_bn < PERBLK) ? s_bn : PERBLK;
    if (tid == 0) ws[OFF_BLKCNT + blockIdx.x] = bn;
    if (tid < bn) ws[OFF_BLKSRC + blockIdx.x * PERBLK + tid] = s_bs[tid];
    if (blockIdx.x == 0 && tid <= SORTMAX) ws[OFF_DEGS + tid] = 0;
}

// Dispatch 2: gather per-block lists -> canonical sorted ids (identical in
// every block) -> R2-proven 1024-block degree scan -> atomic flush to degs.
// Block 0 publishes sorted ids + K.
__global__ __launch_bounds__(256) void count_kernel(
    const int* __restrict__ dst, int* __restrict__ ws) {
    __shared__ int s_n;
    __shared__ int s_ids[SORTMAX + 1];
    __shared__ int s_cnt[SORTMAX + 1];
    const int tid = threadIdx.x;
    if (tid == 0) s_n = 0;
    __syncthreads();

    // gather (order arbitrary; canonicalized by sort)
    for (int b = tid; b < B1; b += 256) {
        const int c = ws[OFF_BLKCNT + b];
        for (int q = 0; q < c; ++q) {
            const int slot = atomicAdd(&s_n, 1);
            if (slot < SORTMAX) s_ids[slot] = ws[OFF_BLKSRC + b * PERBLK + q];
        }
    }
    __syncthreads();
    const int K = (s_n < SORTMAX) ? s_n : SORTMAX;
    const int tot = K + 1;

    // wave-0 rank sort -> identical canonical array in every block
    if (tid < 64) {
        const int v = (tid < K) ? s_ids[tid] : INT_MAX;
        int rank = 0;
        for (int j = 0; j < 64; ++j) {
            const int vj = __shfl(v, j, 64);
            rank += (vj < v) || (vj == v && j < tid);
        }
        __syncthreads();                       // reads of s_ids done before writes
        if (tid < K) s_ids[rank] = v;
        if (tid == 0) s_ids[K] = 2;            // node 2 at entry K
    } else {
        __syncthreads();
    }
    __syncthreads();
    for (int i = tid; i < tot; i += 256) s_cnt[i] = 0;
    __syncthreads();

    // grid-stride degree scan over dst (R2-proven shape)
    const int4* dst4 = (const int4*)dst;
    const int stride = B2 * 256;
    for (int e = blockIdx.x * 256 + tid; e < E4; e += stride) {
        const int4 d = dst4[e];
        for (int i = 0; i < tot; ++i) {
            const int id = s_ids[i];
            const int m = (d.x == id) + (d.y == id) + (d.z == id) + (d.w == id);
            if (m) atomicAdd(&s_cnt[i], m);
        }
    }
    __syncthreads();
    for (int i = tid; i < tot; i += 256)
        if (s_cnt[i]) atomicAdd(&ws[OFF_DEGS + i], s_cnt[i]);
    if (blockIdx.x == 0) {
        for (int i = tid; i < tot; i += 256) ws[OFF_GIDS + i] = s_ids[i];
        if (tid == 0) ws[OFF_GK] = K;
    }
}

// Dispatch 3: node-2 forward. 256 threads = 4 waves; lane j owns channel j.
// ids arrive pre-sorted (canonical) -> deterministic fp order, no sort here.
__global__ __launch_bounds__(256) void final_kernel(
    const float* __restrict__ x,
    const float* __restrict__ Wz, const float* __restrict__ bz,
    const float* __restrict__ Wh, const float* __restrict__ bh,
    const float* __restrict__ LzW, const float* __restrict__ Lzb,
    const float* __restrict__ LhW, const float* __restrict__ Lhb,
    const float* __restrict__ W1, const float* __restrict__ b1,
    const float* __restrict__ gamma_, const float* __restrict__ beta_,
    const float* __restrict__ rmean, const float* __restrict__ rvar,
    const float* __restrict__ W2, const float* __restrict__ b2,
    const int* __restrict__ ws,
    float* __restrict__ out) {
    const int tid  = threadIdx.x;
    const int lane = tid & 63;
    const int w    = tid >> 6;

    __shared__ int   s_ids[SORTMAX + 1];
    __shared__ int   s_dg [SORTMAX + 1];
    __shared__ float s_part[4][HD];
    __shared__ float s_xsum[HD];
    __shared__ float s_cz[HD], s_ch[HD];
    __shared__ float s_r[HD];

    // weight prefetch first: data-independent, hides under the ws-dependent chain
    const float* WB = (w < 2) ? Wz : Wh;
    const float* WC = (w < 2) ? LzW : LhW;
    const int k0 = (w & 1) * 32;
    float wB[32], wC[32], wD[16];
    #pragma unroll
    for (int kk = 0; kk < 32; ++kk) wB[kk] = WB[(size_t)(k0 + kk) * HD + lane];
    #pragma unroll
    for (int kk = 0; kk < 32; ++kk) wC[kk] = WC[(size_t)(k0 + kk) * HD + lane];
    #pragma unroll
    for (int kk = 0; kk < 16; ++kk) wD[kk] = W1[(size_t)(w * 16 + kk) * HD + lane];

    const int K = ws[OFF_GK];
    const int tot = K + 1;
    if (tid < tot) {
        s_ids[tid] = ws[OFF_GIDS + tid];
        s_dg[tid]  = ws[OFF_DEGS + tid];
    }
    __syncthreads();

    // reference deg = indeg + 1 (self-loop)
    const float dinv2 = rsqrtf((float)(s_dg[K] + 1));

    // weighted sum of x rows (canonical sorted order, fixed wave partition)
    float px = 0.f;
    for (int i = w; i < K; i += 4) {
        const int s = s_ids[i];
        const float wt = rsqrtf((float)(s_dg[i] + 1)) * dinv2;
        px += wt * x[(size_t)s * HD + lane];
    }
    if (w == 0) px += (dinv2 * dinv2) * x[2 * HD + lane];   // self-loop
    s_part[w][lane] = px;
    __syncthreads();
    if (w == 0)
        s_xsum[lane] = s_part[0][lane] + s_part[1][lane] + s_part[2][lane] + s_part[3][lane];
    __syncthreads();

    // cz = xsum@Wz + bz ; ch = xsum@Wh + bh
    {
        float acc = 0.f;
        #pragma unroll
        for (int kk = 0; kk < 32; ++kk) acc += s_xsum[k0 + kk] * wB[kk];
        s_part[w][lane] = acc;
    }
    __syncthreads();
    if (w == 0)      s_cz[lane] = s_part[0][lane] + s_part[1][lane] + bz[lane];
    else if (w == 1) s_ch[lane] = s_part[2][lane] + s_part[3][lane] + bh[lane];
    __syncthreads();

    // gate linears (H0 = 0 -> only first HD rows matter)
    {
        const float* c = (w < 2) ? s_cz : s_ch;
        float acc = 0.f;
        #pragma unroll
        for (int kk = 0; kk < 32; ++kk) acc += c[k0 + kk] * wC[kk];
        s_part[w][lane] = acc;
    }
    __syncthreads();
    if (w == 0) {
        const float zdot = s_part[0][lane] + s_part[1][lane] + Lzb[lane];
        const float hdot = s_part[2][lane] + s_part[3][lane] + Lhb[lane];
        const float Zv = 1.f / (1.f + expf(-zdot));
        const float Ht = tanhf(hdot);
        s_r[lane] = fmaxf((1.f - Zv) * Ht, 0.f);   // h = (1-Z)*Ht (H0=0), relu
    }
    __syncthreads();

    // y1 = relu_out @ W1, k-quarter per wave
    {
        float acc = 0.f;
        #pragma unroll
        for (int kk = 0; kk < 16; ++kk) acc += s_r[w * 16 + kk] * wD[kk];
        s_part[w][lane] = acc;
    }
    __syncthreads();

    // BN(eval) + relu + dot with W2 (wave 0)
    if (w == 0) {
        float y1 = s_part[0][lane] + s_part[1][lane] + s_part[2][lane] + s_part[3][lane] + b1[lane];
        const float bn = (y1 - rmean[lane]) * rsqrtf(rvar[lane] + 1e-5f) * gamma_[lane] + beta_[lane];
        const float yr = fmaxf(bn, 0.f);
        float part = yr * W2[lane];
        #pragma unroll
        for (int off = 32; off > 0; off >>= 1)
            part += __shfl_down(part, off, 64);
        if (lane == 0) out[0] = part + b2[0];
    }
}

extern "C" void kernel_launch(void* const* d_in, const int* in_sizes, int n_in,
                              void* d_out, int out_size, void* d_ws, size_t ws_size,
                              hipStream_t stream) {
    const float* x     = (const float*)d_in[0];
    const float* Wz    = (const float*)d_in[1];
    const float* bz    = (const float*)d_in[2];
    // d_in[3]=Wr, d_in[4]=br: dead (R only scales H0==0)
    const float* Wh    = (const float*)d_in[5];
    const float* bh    = (const float*)d_in[6];
    const float* LzW   = (const float*)d_in[7];
    const float* Lzb   = (const float*)d_in[8];
    // d_in[9]=Lr_W, d_in[10]=Lr_b: dead
    const float* LhW   = (const float*)d_in[11];
    const float* Lhb   = (const float*)d_in[12];
    const float* W1    = (const float*)d_in[13];
    const float* b1    = (const float*)d_in[14];
    const float* gam   = (const float*)d_in[15];
    const float* bet   = (const float*)d_in[16];
    const float* rmean = (const float*)d_in[17];
    const float* rvar  = (const float*)d_in[18];
    const float* W2    = (const float*)d_in[19];
    const float* b2    = (const float*)d_in[20];
    const int*   src   = (const int*)d_in[21];
    const int*   dst   = (const int*)d_in[22];

    int* ws = (int*)d_ws;

    collect_kernel<<<B1, 256, 0, stream>>>(src, dst, ws);
    count_kernel<<<B2, 256, 0, stream>>>(dst, ws);
    final_kernel<<<1, 256, 0, stream>>>(x, Wz, bz, Wh, bh, LzW, Lzb, LhW, Lhb,
                                        W1, b1, gam, bet, rmean, rvar, W2, b2,
                                        ws, (float*)d_out);
}